// Round 7
// baseline (101.799 us; speedup 1.0000x reference)
//
#include <hip/hip_runtime.h>

#define NPROP 8192
#define NT 1024
typedef unsigned long long u64;

__device__ __forceinline__ int bucket_of(float s) {
    int b = (int)(s * 8192.0f);
    return b < 0 ? 0 : (b > NPROP - 1 ? NPROP - 1 : b);
}

__device__ __forceinline__ bool iou_gt_thr(float4 a, float4 b) {
    float areaA = (a.z - a.x) * (a.w - a.y);
    float areaB = (b.z - b.x) * (b.w - b.y);
    float lx = fmaxf(a.x, b.x), ly = fmaxf(a.y, b.y);
    float rx = fminf(a.z, b.z), ry = fminf(a.w, b.w);
    float w = fmaxf(rx - lx, 0.0f), h = fmaxf(ry - ly, 0.0f);
    float inter = w * h;
    float uni = areaA + areaB - inter;
    float iou = inter / fmaxf(uni, 1e-6f);
    return iou > 0.3f;
}

// K1: fused LDS counting sort + validity + compaction (single block, no memset)
__global__ __launch_bounds__(NT)
void k_sortall(const float* __restrict__ boxes, const float* __restrict__ scores,
               const float* __restrict__ img,
               float4* __restrict__ srt_box, float* __restrict__ srt_sv,
               float4* __restrict__ cbox, int* __restrict__ crank,
               int* __restrict__ meta) {
    extern __shared__ char smem[];
    u64* keys = (u64*)smem;              // 64 KiB
    int* lo   = (int*)(smem + 65536);    // 32 KiB
    int* pm   = (int*)(smem + 98304);    // 32 KiB (hist -> prefix -> allocator)
    __shared__ int wsum[16], wexcl[16];
    __shared__ int vraw;

    const int tid = threadIdx.x, lane = tid & 63, wave = tid >> 6;

    // 1. load scores (vectorized), build sort keys + buckets
    const float4* s4 = reinterpret_cast<const float4*>(scores);
    float4 sa = s4[tid * 2], sb = s4[tid * 2 + 1];
    float ss[8] = {sa.x, sa.y, sa.z, sa.w, sb.x, sb.y, sb.z, sb.w};
    u64 k[8]; int bk[8];
    #pragma unroll
    for (int u = 0; u < 8; u++) {
        int p = tid * 8 + u;
        k[u] = ((u64)__float_as_uint(ss[u]) << 32) | (u64)(unsigned)(NPROP - 1 - p);
        bk[u] = bucket_of(ss[u]);
    }

    // 2. zero hist in LDS (replaces the 39us fillBufferAligned)
    #pragma unroll
    for (int u = 0; u < 8; u++) pm[tid * 8 + u] = 0;
    __syncthreads();

    // 3. histogram via LDS atomics
    #pragma unroll
    for (int u = 0; u < 8; u++) atomicAdd(&pm[bk[u]], 1);
    __syncthreads();

    // 4. exclusive scan over 8192 bins -> lo (ro) and pm (allocator)
    int h[8]; int tot = 0;
    #pragma unroll
    for (int u = 0; u < 8; u++) { h[u] = pm[tid * 8 + u]; tot += h[u]; }
    int incl = tot;
    #pragma unroll
    for (int off = 1; off < 64; off <<= 1) {
        int n = __shfl_up(incl, off, 64);
        if (lane >= off) incl += n;
    }
    if (lane == 63) wsum[wave] = incl;
    __syncthreads();
    if (tid == 0) {
        int acc = 0;
        #pragma unroll
        for (int w = 0; w < 16; w++) { int t = wsum[w]; wexcl[w] = acc; acc += t; }
    }
    __syncthreads();
    int run = wexcl[wave] + (incl - tot);
    #pragma unroll
    for (int u = 0; u < 8; u++) {
        lo[tid * 8 + u] = run;
        pm[tid * 8 + u] = run;
        run += h[u];
    }
    __syncthreads();

    // 5. scatter keys into bucket-grouped LDS order
    #pragma unroll
    for (int u = 0; u < 8; u++) {
        int slot = atomicAdd(&pm[bk[u]], 1);
        keys[slot] = k[u];
    }
    __syncthreads();

    // 6. exact stable rank (in-bucket count from LDS) + validity + global scatter
    float ix1 = img[0], iy1 = img[1], ix2 = img[2], iy2 = img[3];
    float img_area = (ix2 - ix1) * (iy2 - iy1);
    #pragma unroll
    for (int u = 0; u < 8; u++) {
        int b = bk[u];
        int l = lo[b], hi = pm[b];      // post-scatter pm[b] == bucket end
        int cnt = 0;
        for (int q = l; q < hi; q++) cnt += (keys[q] < k[u]) ? 1 : 0;
        int pos = NPROP - 1 - (l + cnt);            // descending, stable
        int idx = NPROP - 1 - (int)(unsigned)(k[u] & 0xffffffffull);
        float4 bx = reinterpret_cast<const float4*>(boxes)[idx];
        float w = bx.z - bx.x, hh = bx.w - bx.y;
        float ratio = w / (hh + 1e-12f);
        bool vs = (ratio > 0.25f) && (ratio < 4.0f);
        float lx = fmaxf(ix1, bx.x), ly = fmaxf(iy1, bx.y);
        float rx = fminf(ix2, bx.z), ry = fminf(iy2, bx.w);
        float iw = fmaxf(rx - lx, 0.0f), ih = fmaxf(ry - ly, 0.0f);
        float iof = (iw * ih) / fmaxf(img_area, 1e-6f);
        bool vf = vs && (iof > 0.01f) && (ss[u] > 0.85f);
        srt_box[pos] = bx;
        srt_sv[pos] = __uint_as_float(__float_as_uint(ss[u]) | (vf ? 0x80000000u : 0u));
    }
    __syncthreads();   // block-level visibility of the global scatters

    // 7. compaction over sorted order (contiguous re-read, L1/L2 hits)
    bool vf2[8]; float4 bx2[8]; int tot2 = 0;
    #pragma unroll
    for (int u = 0; u < 8; u++) {
        int p = tid * 8 + u;
        bx2[u] = srt_box[p];
        vf2[u] = (__float_as_uint(srt_sv[p]) >> 31) != 0;
        tot2 += vf2[u] ? 1 : 0;
    }
    int incl2 = tot2;
    #pragma unroll
    for (int off = 1; off < 64; off <<= 1) {
        int n = __shfl_up(incl2, off, 64);
        if (lane >= off) incl2 += n;
    }
    if (lane == 63) wsum[wave] = incl2;
    __syncthreads();
    if (tid == 0) {
        int acc = 0;
        #pragma unroll
        for (int w = 0; w < 16; w++) { int t = wsum[w]; wexcl[w] = acc; acc += t; }
        vraw = acc;
        int V = acc == 0 ? 1 : acc;
        meta[0] = V;
        meta[1] = (V + 63) >> 6;
    }
    __syncthreads();
    int base = wexcl[wave] + (incl2 - tot2);
    #pragma unroll
    for (int u = 0; u < 8; u++) {
        int p = tid * 8 + u;
        if (vf2[u]) { crank[p] = base; cbox[base] = bx2[u]; base++; }
        else crank[p] = -1;
    }
    if (vraw == 0 && tid == 0) { crank[0] = 0; cbox[0] = bx2[0]; }
}

// K2: suppression mask matrix — wave per row, lane per column, ballot per word
__global__ __launch_bounds__(256)
void k_mask(const float4* __restrict__ cbox, const int* __restrict__ meta,
            u64* __restrict__ mask) {
    const int V = meta[0], W = meta[1];
    const int lane = threadIdx.x & 63;
    int gw = blockIdx.x * 4 + (threadIdx.x >> 6);
    for (int r = gw; r < V; r += 1024) {
        float4 br = cbox[r];
        for (int w = (r >> 6); w < W; w++) {
            int col = w * 64 + lane;
            bool ok = (col < V) && (col > r) && iou_gt_thr(br, cbox[col]);
            u64 bal = __ballot(ok);
            if (lane == 0) mask[(u64)r * W + w] = bal;
        }
    }
}

// K3: serial greedy resolve (rem in LDS) + fused final output
__global__ __launch_bounds__(NT)
void k_resolve_out(const u64* __restrict__ mask, const int* __restrict__ meta,
                   const float4* __restrict__ srt_box, const float* __restrict__ srt_sv,
                   const int* __restrict__ crank, float* __restrict__ out) {
    __shared__ u64 rem[NPROP / 64];
    const int V = meta[0], W = meta[1];
    const int tid = threadIdx.x, lane = tid & 63, wave = tid >> 6;

    for (int w = tid; w < NPROP / 64; w += NT) {
        int b0 = w * 64; u64 m;
        if (b0 >= V) m = ~0ull;
        else if (b0 + 64 <= V) m = 0ull;
        else m = (~0ull) << (V - b0);
        rem[w] = m;
    }
    __syncthreads();

    for (int b = 0; b < W; b++) {
        const int rb0 = b * 64;
        // Phase B: intra-block resolve, scalar readlane chain
        if (tid < 64) {
            int row = rb0 + tid;
            u64 d = (row < V) ? mask[(u64)row * W + b] : 0ull;
            unsigned dl0 = (unsigned)(d & 0xffffffffull);
            unsigned dh0 = (unsigned)(d >> 32);
            u64 r = rem[b];
            #pragma unroll
            for (int i = 0; i < 64; i++) {
                unsigned dl = (unsigned)__builtin_amdgcn_readlane((int)dl0, i);
                unsigned dh = (unsigned)__builtin_amdgcn_readlane((int)dh0, i);
                u64 di = ((u64)dh << 32) | (u64)dl;
                r |= ((r >> i) & 1ull) ? 0ull : di;
            }
            if (tid == 0) rem[b] = r;
        }
        __syncthreads();
        // Apply: kept rows OR their mask words into rem (parallel)
        u64 keptm = ~rem[b];
        #pragma unroll
        for (int t = 0; t < 4; t++) {
            int rl = wave * 4 + t;
            int row = rb0 + rl;
            if (row < V && ((keptm >> rl) & 1ull)) {
                for (int w = b + 1 + lane; w < W; w += 64) {
                    u64 m = mask[(u64)row * W + w];
                    if (m) atomicOr((unsigned long long*)&rem[w], m);
                }
            }
        }
        __syncthreads();
    }

    // fused final output: [N,5]*keep + keep mask, vectorized stores
    float ob[40]; float om[8];
    #pragma unroll
    for (int u = 0; u < 8; u++) {
        int p = tid * 8 + u;
        float4 b = srt_box[p];
        unsigned svb = __float_as_uint(srt_sv[p]);
        float s = __uint_as_float(svb & 0x7fffffffu);
        int kk = crank[p];
        bool keep = (kk >= 0) && !((rem[kk >> 6] >> (kk & 63)) & 1ull);
        float m = keep ? 1.0f : 0.0f;
        ob[u * 5 + 0] = b.x * m;
        ob[u * 5 + 1] = b.y * m;
        ob[u * 5 + 2] = b.z * m;
        ob[u * 5 + 3] = b.w * m;
        ob[u * 5 + 4] = s * m;
        om[u] = m;
    }
    float4* o4 = reinterpret_cast<float4*>(out) + tid * 10;
    #pragma unroll
    for (int q = 0; q < 10; q++)
        o4[q] = make_float4(ob[q * 4 + 0], ob[q * 4 + 1], ob[q * 4 + 2], ob[q * 4 + 3]);
    float4* m4 = reinterpret_cast<float4*>(out + NPROP * 5) + tid * 2;
    m4[0] = make_float4(om[0], om[1], om[2], om[3]);
    m4[1] = make_float4(om[4], om[5], om[6], om[7]);
}

extern "C" void kernel_launch(void* const* d_in, const int* in_sizes, int n_in,
                              void* d_out, int out_size, void* d_ws, size_t ws_size,
                              hipStream_t stream) {
    const float* boxes  = (const float*)d_in[0];
    const float* scores = (const float*)d_in[1];
    const float* img    = (const float*)d_in[2];
    char* ws = (char*)d_ws;
    float4* srt_box = (float4*)(ws + 0);        // 128 KiB
    float*  srt_sv  = (float*)(ws + 131072);    //  32 KiB
    float4* cbox    = (float4*)(ws + 163840);   // 128 KiB
    int*    crank   = (int*)(ws + 294912);      //  32 KiB
    int*    meta    = (int*)(ws + 327680);      //  1 KiB (padded)
    u64*    mask    = (u64*)(ws + 328704);      //  V*W*8 B
    float* out = (float*)d_out;

    k_sortall<<<1, NT, 131072, stream>>>(boxes, scores, img, srt_box, srt_sv,
                                         cbox, crank, meta);
    k_mask<<<256, 256, 0, stream>>>(cbox, meta, mask);
    k_resolve_out<<<1, NT, 0, stream>>>(mask, meta, srt_box, srt_sv, crank, out);
}